// Round 1
// baseline (15827.557 us; speedup 1.0000x reference)
//
#include <hip/hip_runtime.h>
#include <hip/hip_bf16.h>

#define TDIM 4096
#define BDIM 64
#define FDIM 128
#define HDIM 512
#define ODIM 128
#define KWIN 32

typedef __attribute__((ext_vector_type(8))) short short8;
typedef __attribute__((ext_vector_type(4))) float floatx4;

__device__ __forceinline__ unsigned short f2bf(float f) {
  unsigned int u = __float_as_uint(f);
  u += 0x7fffu + ((u >> 16) & 1u);
  return (unsigned short)(u >> 16);
}
__device__ __forceinline__ float bf2f(unsigned short s) {
  return __uint_as_float(((unsigned int)s) << 16);
}

// ---------------------------------------------------------------------------
// Kernel 1: fractional differencing + input projection, writes xp in a
// lane-permuted packed-bf16 layout for the scan kernel.
// xp value for (t, b, h):  g=b>>4, w=h>>7, nt=(h>>4)&7, j=(b&3)*4+(nt>>1),
// lane=((b>>2)&3)*16+(h&15), half=(nt&1).
// dword index = (((t*16 + g*4 + w)*16 + j)*64 + lane
// grid (T/64, B), block 256 (4 waves)
// ---------------------------------------------------------------------------
__global__ __launch_bounds__(256, 1)
void prep_kernel(const float* __restrict__ x, const float* __restrict__ bd,
                 const float* __restrict__ Wih, const float* __restrict__ bih,
                 const float* __restrict__ bhh, unsigned int* __restrict__ xp)
{
  __shared__ __align__(16) float xs[96 * 128];   // 48 KB x slab (t0-32..t0+63)
  __shared__ float wpi[33 * 128];                // 16.9 KB pi_j weights
  __shared__ __align__(16) short xf[64 * 136];   // 17.4 KB frac-diffed tile (bf16)

  const int tid = threadIdx.x;
  const int tc = blockIdx.x, b = blockIdx.y;
  const int t0 = tc * 64;

  // --- ARFIMA (1-B)^d coefficients, pi_0..pi_32 per feature ---
  if (tid < 128) {
    float d = 0.5f / (1.0f + __expf(-bd[tid]));
    float pi = 1.0f;
    wpi[tid] = pi;
    for (int i = 0; i < 32; ++i) {
      pi *= ((float)i - d) / (float)(i + 1);
      wpi[(i + 1) * 128 + tid] = pi;
    }
  }

  // --- load x slab [96][128] ---
  #pragma unroll
  for (int rep = 0; rep < 12; ++rep) {
    int flat = rep * 256 + tid;
    int row = flat >> 5, c4 = flat & 31;
    int t = t0 + row - 32;
    floatx4 v = {0.f, 0.f, 0.f, 0.f};
    if (t >= 0) v = *(const floatx4*)(x + ((size_t)t * BDIM + b) * FDIM + (size_t)c4 * 4);
    *(floatx4*)&xs[row * 128 + c4 * 4] = v;
  }
  __syncthreads();

  // --- causal depthwise conv: x~[t] = sum_{j=0..32} pi_j x[t-j] ---
  {
    const int f = tid & 127, tq = tid >> 7;
    float wv[33];
    #pragma unroll
    for (int j = 0; j < 33; ++j) wv[j] = wpi[j * 128 + f];
    for (int s = 0; s < 32; ++s) {
      int tl = tq * 32 + s;
      float acc = 0.f;
      #pragma unroll
      for (int j = 0; j < 33; ++j) acc += wv[j] * xs[(tl + 32 - j) * 128 + f];
      xf[tl * 136 + f] = (short)f2bf(acc);
    }
  }
  __syncthreads();

  // --- GEMM: [64 x 128] @ [128 x 512], wave w covers cols [w*128, w*128+128) ---
  const int w = tid >> 6, l = tid & 63;
  const int lr = l & 15, lq = l >> 4;

  short8 wf[4][8];
  float bias[8];
  #pragma unroll
  for (int kc = 0; kc < 4; ++kc)
    #pragma unroll
    for (int nt = 0; nt < 8; ++nt) {
      int n = w * 128 + nt * 16 + lr;
      const float* src = Wih + (size_t)n * FDIM + kc * 32 + lq * 8;
      floatx4 f0 = *(const floatx4*)src;
      floatx4 f1 = *(const floatx4*)(src + 4);
      short8 s;
      s[0] = (short)f2bf(f0[0]); s[1] = (short)f2bf(f0[1]);
      s[2] = (short)f2bf(f0[2]); s[3] = (short)f2bf(f0[3]);
      s[4] = (short)f2bf(f1[0]); s[5] = (short)f2bf(f1[1]);
      s[6] = (short)f2bf(f1[2]); s[7] = (short)f2bf(f1[3]);
      wf[kc][nt] = s;
    }
  #pragma unroll
  for (int nt = 0; nt < 8; ++nt) {
    int n = w * 128 + nt * 16 + lr;
    bias[nt] = bih[n] + bhh[n];
  }

  floatx4 acc[4][8];
  #pragma unroll
  for (int m = 0; m < 4; ++m)
    #pragma unroll
    for (int kc = 0; kc < 4; ++kc) {
      short8 a = *(const short8*)&xf[(m * 16 + lr) * 136 + kc * 32 + lq * 8];
      #pragma unroll
      for (int nt = 0; nt < 8; ++nt) {
        floatx4 c = (kc == 0) ? (floatx4){0.f, 0.f, 0.f, 0.f} : acc[m][nt];
        acc[m][nt] = __builtin_amdgcn_mfma_f32_16x16x32_bf16(a, wf[kc][nt], c, 0, 0, 0);
      }
    }

  // --- store packed bf16 pairs into permuted xp layout ---
  const int g = b >> 4, qs = (b >> 2) & 3, r = b & 3;
  #pragma unroll
  for (int m = 0; m < 4; ++m)
    #pragma unroll
    for (int rr = 0; rr < 4; ++rr)
      #pragma unroll
      for (int a2 = 0; a2 < 4; ++a2) {
        float v0 = acc[m][2 * a2][rr] + bias[2 * a2];
        float v1 = acc[m][2 * a2 + 1][rr] + bias[2 * a2 + 1];
        unsigned int pk = (unsigned int)f2bf(v0) | ((unsigned int)f2bf(v1) << 16);
        int t = t0 + m * 16 + lq * 4 + rr;
        int j = r * 4 + a2;
        int lane2 = qs * 16 + lr;
        size_t idx = ((((size_t)t * 16 + g * 4 + w) * 16 + j) * 64 + lane2);
        xp[idx] = pk;
      }
}

// ---------------------------------------------------------------------------
// Kernel 2: the recurrence. 4 workgroups (batch groups of 16), 256 threads
// (4 waves, 1/SIMD, up to 512 VGPRs). W_hh bf16: K-chunks 0..11 resident in
// VGPRs (384/wave), chunks 12..15 in LDS (128 KB, pre-swizzled fragments).
// h lives in LDS [16][520] bf16. Also writes final outputs + hT.
// ---------------------------------------------------------------------------
__global__ __launch_bounds__(256, 1)
void scan_kernel(const float* __restrict__ Whh, const unsigned int* __restrict__ xp,
                 const float* __restrict__ Who, const float* __restrict__ bho,
                 float* __restrict__ out)
{
  __shared__ __align__(16) short h_lds[16 * 520];        // 16.6 KB
  __shared__ __align__(16) short8 w_lds[4 * 4 * 8 * 64]; // 128 KB

  const int tid = threadIdx.x;
  const int g = blockIdx.x;                 // batch group 0..3
  const int w = tid >> 6, l = tid & 63;
  const int lr = l & 15, lq = l >> 4;

  // --- load W_hh fragments (B operand: B[k][n] = W_hh[n][k]) ---
  short8 wreg[96];
  #pragma unroll
  for (int kc = 0; kc < 16; ++kc)
    #pragma unroll
    for (int nt = 0; nt < 8; ++nt) {
      int n = w * 128 + nt * 16 + lr;
      const float* src = Whh + (size_t)n * HDIM + kc * 32 + lq * 8;
      floatx4 f0 = *(const floatx4*)src;
      floatx4 f1 = *(const floatx4*)(src + 4);
      short8 s;
      s[0] = (short)f2bf(f0[0]); s[1] = (short)f2bf(f0[1]);
      s[2] = (short)f2bf(f0[2]); s[3] = (short)f2bf(f0[3]);
      s[4] = (short)f2bf(f1[0]); s[5] = (short)f2bf(f1[1]);
      s[6] = (short)f2bf(f1[2]); s[7] = (short)f2bf(f1[3]);
      if (kc < 12) wreg[kc * 8 + nt] = s;
      else w_lds[(((kc - 12) * 4 + w) * 8 + nt) * 64 + l] = s;
    }

  for (int i = tid; i < 16 * 520; i += 256) h_lds[i] = 0;
  __syncthreads();

  const unsigned int* xpb = xp + ((size_t)(g * 4 + w) * 16) * 64 + l;

  floatx4 acc[8];
  #pragma unroll 1
  for (int t = 0; t < TDIM; ++t) {
    // xp loads for this step (consumed after the MFMA phase; latency hidden)
    unsigned int u[16];
    const unsigned int* p = xpb + (size_t)t * 16384;
    #pragma unroll
    for (int j = 0; j < 16; ++j) u[j] = p[j * 64];

    // --- h @ W_hh^T for this wave's 128-col slice ---
    #pragma unroll
    for (int kc = 0; kc < 16; ++kc) {
      short8 a = *(const short8*)&h_lds[lr * 520 + kc * 32 + lq * 8];
      #pragma unroll
      for (int nt = 0; nt < 8; ++nt) {
        short8 bfrag = (kc < 12) ? wreg[kc * 8 + nt]
                                 : w_lds[(((kc - 12) * 4 + w) * 8 + nt) * 64 + l];
        floatx4 c = (kc == 0) ? (floatx4){0.f, 0.f, 0.f, 0.f} : acc[nt];
        acc[nt] = __builtin_amdgcn_mfma_f32_16x16x32_bf16(a, bfrag, c, 0, 0, 0);
      }
    }
    __syncthreads();   // all waves done reading h_lds

    // --- add xp, tanh, write new h ---
    #pragma unroll
    for (int nt = 0; nt < 8; ++nt)
      #pragma unroll
      for (int rr = 0; rr < 4; ++rr) {
        int j = rr * 4 + (nt >> 1);
        unsigned int dv = u[j];
        unsigned short hb = (nt & 1) ? (unsigned short)(dv >> 16)
                                     : (unsigned short)(dv & 0xffffu);
        float pre = acc[nt][rr] + bf2f(hb);
        float e = __expf(2.0f * pre);
        float tv = 1.0f - 2.0f / (e + 1.0f);
        h_lds[(lq * 4 + rr) * 520 + w * 128 + nt * 16 + lr] = (short)f2bf(tv);
      }
    __syncthreads();
  }

  // --- write hT (output 1), bf16-rounded h (error << threshold) ---
  for (int i = tid; i < 16 * 512; i += 256) {
    int row = i >> 9, col = i & 511;
    out[(size_t)ODIM * BDIM + ((size_t)(g * 16 + row)) * HDIM + col] =
        bf2f((unsigned short)h_lds[row * 520 + col]);
  }

  // --- output projection: outputs = hT @ W_ho^T + b_ho (wave w: o in [w*32, w*32+32)) ---
  floatx4 oacc[2];
  #pragma unroll
  for (int kc = 0; kc < 16; ++kc) {
    short8 a = *(const short8*)&h_lds[lr * 520 + kc * 32 + lq * 8];
    #pragma unroll
    for (int nt = 0; nt < 2; ++nt) {
      int o = w * 32 + nt * 16 + lr;
      const float* src = Who + (size_t)o * HDIM + kc * 32 + lq * 8;
      floatx4 f0 = *(const floatx4*)src;
      floatx4 f1 = *(const floatx4*)(src + 4);
      short8 s;
      s[0] = (short)f2bf(f0[0]); s[1] = (short)f2bf(f0[1]);
      s[2] = (short)f2bf(f0[2]); s[3] = (short)f2bf(f0[3]);
      s[4] = (short)f2bf(f1[0]); s[5] = (short)f2bf(f1[1]);
      s[6] = (short)f2bf(f1[2]); s[7] = (short)f2bf(f1[3]);
      floatx4 c = (kc == 0) ? (floatx4){0.f, 0.f, 0.f, 0.f} : oacc[nt];
      oacc[nt] = __builtin_amdgcn_mfma_f32_16x16x32_bf16(a, s, c, 0, 0, 0);
    }
  }
  #pragma unroll
  for (int nt = 0; nt < 2; ++nt)
    #pragma unroll
    for (int rr = 0; rr < 4; ++rr) {
      int o = w * 32 + nt * 16 + lr;
      int row = lq * 4 + rr;
      out[((size_t)(g * 16 + row)) * ODIM + o] = oacc[nt][rr] + bho[o];
    }
}

// ---------------------------------------------------------------------------
extern "C" void kernel_launch(void* const* d_in, const int* in_sizes, int n_in,
                              void* d_out, int out_size, void* d_ws, size_t ws_size,
                              hipStream_t stream) {
  const float* x   = (const float*)d_in[0];
  const float* bd  = (const float*)d_in[1];
  const float* Wih = (const float*)d_in[2];
  const float* bih = (const float*)d_in[3];
  const float* Whh = (const float*)d_in[4];
  const float* bhh = (const float*)d_in[5];
  const float* Who = (const float*)d_in[6];
  const float* bho = (const float*)d_in[7];
  float* out = (float*)d_out;
  unsigned int* xp = (unsigned int*)d_ws;   // needs T*B*H*2 = 268.4 MB

  prep_kernel<<<dim3(TDIM / 64, BDIM), 256, 0, stream>>>(x, bd, Wih, bih, bhh, xp);
  scan_kernel<<<dim3(4), 256, 0, stream>>>(Whh, xp, Who, bho, out);
}

// Round 2
// 9431.039 us; speedup vs baseline: 1.6782x; 1.6782x over previous
//
#include <hip/hip_runtime.h>
#include <hip/hip_bf16.h>

#define TDIM 4096
#define BDIM 64
#define FDIM 128
#define HDIM 512
#define ODIM 128
#define KWIN 32

typedef __attribute__((ext_vector_type(8))) short short8;
typedef __attribute__((ext_vector_type(4))) float floatx4;

__device__ __forceinline__ unsigned short f2bf(float f) {
  unsigned int u = __float_as_uint(f);
  u += 0x7fffu + ((u >> 16) & 1u);
  return (unsigned short)(u >> 16);
}
__device__ __forceinline__ float bf2f(unsigned short s) {
  return __uint_as_float(((unsigned int)s) << 16);
}

// ---------------------------------------------------------------------------
// Kernel 1: fractional differencing + input projection.
// xp layout (dwords, packed bf16 pairs) for the 8-wave scan:
// value (t, b, h): g=b>>4, ws=h>>6, nt=(h>>4)&3, pair a=nt>>1, half=nt&1,
// j=(b&3)*2+a, lane=((b>>2)&3)*16+(h&15).
// idx = t*16384 + (g*8+ws)*512 + j*64 + lane
// grid (T/64, B), block 256 (4 waves; wave wp covers scan waves 2wp, 2wp+1)
// ---------------------------------------------------------------------------
__global__ __launch_bounds__(256, 1)
void prep_kernel(const float* __restrict__ x, const float* __restrict__ bd,
                 const float* __restrict__ Wih, const float* __restrict__ bih,
                 const float* __restrict__ bhh, unsigned int* __restrict__ xp)
{
  __shared__ __align__(16) float xs[96 * 128];   // 48 KB x slab (t0-32..t0+63)
  __shared__ float wpi[33 * 128];                // 16.9 KB pi_j weights
  __shared__ __align__(16) short xf[64 * 136];   // 17.4 KB frac-diffed tile (bf16)

  const int tid = threadIdx.x;
  const int tc = blockIdx.x, b = blockIdx.y;
  const int t0 = tc * 64;

  // --- ARFIMA (1-B)^d coefficients, pi_0..pi_32 per feature ---
  if (tid < 128) {
    float d = 0.5f / (1.0f + __expf(-bd[tid]));
    float pi = 1.0f;
    wpi[tid] = pi;
    for (int i = 0; i < 32; ++i) {
      pi *= ((float)i - d) / (float)(i + 1);
      wpi[(i + 1) * 128 + tid] = pi;
    }
  }

  // --- load x slab [96][128] ---
  #pragma unroll
  for (int rep = 0; rep < 12; ++rep) {
    int flat = rep * 256 + tid;
    int row = flat >> 5, c4 = flat & 31;
    int t = t0 + row - 32;
    floatx4 v = {0.f, 0.f, 0.f, 0.f};
    if (t >= 0) v = *(const floatx4*)(x + ((size_t)t * BDIM + b) * FDIM + (size_t)c4 * 4);
    *(floatx4*)&xs[row * 128 + c4 * 4] = v;
  }
  __syncthreads();

  // --- causal depthwise conv: x~[t] = sum_{j=0..32} pi_j x[t-j] ---
  {
    const int f = tid & 127, tq = tid >> 7;
    float wv[33];
    #pragma unroll
    for (int j = 0; j < 33; ++j) wv[j] = wpi[j * 128 + f];
    for (int s = 0; s < 32; ++s) {
      int tl = tq * 32 + s;
      float acc = 0.f;
      #pragma unroll
      for (int j = 0; j < 33; ++j) acc += wv[j] * xs[(tl + 32 - j) * 128 + f];
      xf[tl * 136 + f] = (short)f2bf(acc);
    }
  }
  __syncthreads();

  // --- GEMM: [64 x 128] @ [128 x 512], prep wave w covers cols [w*128, w*128+128) ---
  const int w = tid >> 6, l = tid & 63;
  const int lr = l & 15, lq = l >> 4;

  short8 wf[4][8];
  float bias[8];
  #pragma unroll
  for (int kc = 0; kc < 4; ++kc)
    #pragma unroll
    for (int nt = 0; nt < 8; ++nt) {
      int n = w * 128 + nt * 16 + lr;
      const float* src = Wih + (size_t)n * FDIM + kc * 32 + lq * 8;
      floatx4 f0 = *(const floatx4*)src;
      floatx4 f1 = *(const floatx4*)(src + 4);
      short8 s;
      s[0] = (short)f2bf(f0[0]); s[1] = (short)f2bf(f0[1]);
      s[2] = (short)f2bf(f0[2]); s[3] = (short)f2bf(f0[3]);
      s[4] = (short)f2bf(f1[0]); s[5] = (short)f2bf(f1[1]);
      s[6] = (short)f2bf(f1[2]); s[7] = (short)f2bf(f1[3]);
      wf[kc][nt] = s;
    }
  #pragma unroll
  for (int nt = 0; nt < 8; ++nt) {
    int n = w * 128 + nt * 16 + lr;
    bias[nt] = bih[n] + bhh[n];
  }

  floatx4 acc[4][8];
  #pragma unroll
  for (int m = 0; m < 4; ++m)
    #pragma unroll
    for (int kc = 0; kc < 4; ++kc) {
      short8 a = *(const short8*)&xf[(m * 16 + lr) * 136 + kc * 32 + lq * 8];
      #pragma unroll
      for (int nt = 0; nt < 8; ++nt) {
        floatx4 c = (kc == 0) ? (floatx4){0.f, 0.f, 0.f, 0.f} : acc[m][nt];
        acc[m][nt] = __builtin_amdgcn_mfma_f32_16x16x32_bf16(a, wf[kc][nt], c, 0, 0, 0);
      }
    }

  // --- store packed bf16 pairs into permuted xp layout (8-wave scan geometry) ---
  const int g = b >> 4;
  const int lane2 = ((b >> 2) & 3) * 16 + lr;
  #pragma unroll
  for (int m = 0; m < 4; ++m)
    #pragma unroll
    for (int rr = 0; rr < 4; ++rr)
      #pragma unroll
      for (int c = 0; c < 4; ++c) {            // c indexes even nt8 pairs {0,1},{2,3},{4,5},{6,7}
        float v0 = acc[m][2 * c][rr] + bias[2 * c];
        float v1 = acc[m][2 * c + 1][rr] + bias[2 * c + 1];
        unsigned int pk = (unsigned int)f2bf(v0) | ((unsigned int)f2bf(v1) << 16);
        int t = t0 + m * 16 + lq * 4 + rr;
        int ws = w * 2 + (c >> 1);             // scan wave
        int j = (b & 3) * 2 + (c & 1);
        size_t idx = (size_t)t * 16384 + (size_t)((g * 8 + ws) * 512 + j * 64 + lane2);
        xp[idx] = pk;
      }
}

// ---------------------------------------------------------------------------
// Kernel 2: the recurrence. 4 workgroups (batch groups of 16), 512 threads
// (8 waves, 2/SIMD, <=256 VGPR each). Wave w covers h cols [w*64, w*64+64).
// W_hh bf16 fragments: K-chunks 0..11 in VGPRs (192/wave), 12..15 in LDS
// (128 KB). h in LDS [16][520] bf16. Writes final outputs + hT.
// ---------------------------------------------------------------------------
__global__ __launch_bounds__(512, 2)
void scan_kernel(const float* __restrict__ Whh, const unsigned int* __restrict__ xp,
                 const float* __restrict__ Who, const float* __restrict__ bho,
                 float* __restrict__ out)
{
  __shared__ __align__(16) short h_lds[16 * 520];        // 16.6 KB
  __shared__ __align__(16) short8 w_lds[4 * 8 * 4 * 64]; // 128 KB [(kc-12)][w][nt][lane]

  const int tid = threadIdx.x;
  const int g = blockIdx.x;                 // batch group 0..3
  const int w = tid >> 6, l = tid & 63;     // wave 0..7
  const int lr = l & 15, lq = l >> 4;

  // --- load W_hh fragments (B operand: B[k][n] = W_hh[n][k]) ---
  short8 wreg[48];
  #pragma unroll
  for (int kc = 0; kc < 16; ++kc)
    #pragma unroll
    for (int nt = 0; nt < 4; ++nt) {
      int n = w * 64 + nt * 16 + lr;
      const float* src = Whh + (size_t)n * HDIM + kc * 32 + lq * 8;
      floatx4 f0 = *(const floatx4*)src;
      floatx4 f1 = *(const floatx4*)(src + 4);
      short8 s;
      s[0] = (short)f2bf(f0[0]); s[1] = (short)f2bf(f0[1]);
      s[2] = (short)f2bf(f0[2]); s[3] = (short)f2bf(f0[3]);
      s[4] = (short)f2bf(f1[0]); s[5] = (short)f2bf(f1[1]);
      s[6] = (short)f2bf(f1[2]); s[7] = (short)f2bf(f1[3]);
      if (kc < 12) wreg[kc * 4 + nt] = s;
      else w_lds[(((kc - 12) * 8 + w) * 4 + nt) * 64 + l] = s;
    }

  for (int i = tid; i < 16 * 520; i += 512) h_lds[i] = 0;
  __syncthreads();

  const unsigned int* xpb = xp + (size_t)((g * 8 + w) * 512 + l);

  floatx4 acc[4];
  #pragma unroll 1
  for (int t = 0; t < TDIM; ++t) {
    // xp loads for this step (consumed after the MFMA phase; latency hidden)
    unsigned int u[8];
    const unsigned int* p = xpb + (size_t)t * 16384;
    #pragma unroll
    for (int j = 0; j < 8; ++j) u[j] = p[j * 64];

    // --- h @ W_hh^T for this wave's 64-col slice ---
    #pragma unroll
    for (int kc = 0; kc < 16; ++kc) {
      short8 a = *(const short8*)&h_lds[lr * 520 + kc * 32 + lq * 8];
      #pragma unroll
      for (int nt = 0; nt < 4; ++nt) {
        short8 bfrag = (kc < 12) ? wreg[kc * 4 + nt]
                                 : w_lds[(((kc - 12) * 8 + w) * 4 + nt) * 64 + l];
        floatx4 c = (kc == 0) ? (floatx4){0.f, 0.f, 0.f, 0.f} : acc[nt];
        acc[nt] = __builtin_amdgcn_mfma_f32_16x16x32_bf16(a, bfrag, c, 0, 0, 0);
      }
    }
    __syncthreads();   // all waves done reading h_lds

    // --- add xp, tanh (exp + fast rcp), write new h ---
    #pragma unroll
    for (int nt = 0; nt < 4; ++nt)
      #pragma unroll
      for (int rr = 0; rr < 4; ++rr) {
        int j = rr * 2 + (nt >> 1);
        unsigned int dv = u[j];
        unsigned short hb = (nt & 1) ? (unsigned short)(dv >> 16)
                                     : (unsigned short)(dv & 0xffffu);
        float pre = acc[nt][rr] + bf2f(hb);
        float e = __expf(2.0f * pre);
        float r = __builtin_amdgcn_rcpf(e + 1.0f);
        float tv = 1.0f - 2.0f * r;
        h_lds[(lq * 4 + rr) * 520 + w * 64 + nt * 16 + lr] = (short)f2bf(tv);
      }
    __syncthreads();
  }

  // --- write hT (output 1), bf16-rounded h (error << threshold) ---
  for (int i = tid; i < 16 * 512; i += 512) {
    int row = i >> 9, col = i & 511;
    out[(size_t)ODIM * BDIM + ((size_t)(g * 16 + row)) * HDIM + col] =
        bf2f((unsigned short)h_lds[row * 520 + col]);
  }

  // --- output projection: outputs = hT @ W_ho^T + b_ho (wave w: o in [w*16, w*16+16)) ---
  floatx4 oacc;
  #pragma unroll
  for (int kc = 0; kc < 16; ++kc) {
    short8 a = *(const short8*)&h_lds[lr * 520 + kc * 32 + lq * 8];
    int o = w * 16 + lr;
    const float* src = Who + (size_t)o * HDIM + kc * 32 + lq * 8;
    floatx4 f0 = *(const floatx4*)src;
    floatx4 f1 = *(const floatx4*)(src + 4);
    short8 s;
    s[0] = (short)f2bf(f0[0]); s[1] = (short)f2bf(f0[1]);
    s[2] = (short)f2bf(f0[2]); s[3] = (short)f2bf(f0[3]);
    s[4] = (short)f2bf(f1[0]); s[5] = (short)f2bf(f1[1]);
    s[6] = (short)f2bf(f1[2]); s[7] = (short)f2bf(f1[3]);
    floatx4 c = (kc == 0) ? (floatx4){0.f, 0.f, 0.f, 0.f} : oacc;
    oacc = __builtin_amdgcn_mfma_f32_16x16x32_bf16(a, s, c, 0, 0, 0);
  }
  #pragma unroll
  for (int rr = 0; rr < 4; ++rr) {
    int o = w * 16 + lr;
    int row = lq * 4 + rr;
    out[((size_t)(g * 16 + row)) * ODIM + o] = oacc[rr] + bho[o];
  }
}

// ---------------------------------------------------------------------------
extern "C" void kernel_launch(void* const* d_in, const int* in_sizes, int n_in,
                              void* d_out, int out_size, void* d_ws, size_t ws_size,
                              hipStream_t stream) {
  const float* x   = (const float*)d_in[0];
  const float* bd  = (const float*)d_in[1];
  const float* Wih = (const float*)d_in[2];
  const float* bih = (const float*)d_in[3];
  const float* Whh = (const float*)d_in[4];
  const float* bhh = (const float*)d_in[5];
  const float* Who = (const float*)d_in[6];
  const float* bho = (const float*)d_in[7];
  float* out = (float*)d_out;
  unsigned int* xp = (unsigned int*)d_ws;   // needs T*B*H*2 = 268.4 MB

  prep_kernel<<<dim3(TDIM / 64, BDIM), 256, 0, stream>>>(x, bd, Wih, bih, bhh, xp);
  scan_kernel<<<dim3(4), 512, 0, stream>>>(Whh, xp, Who, bho, out);
}